// Round 3
// baseline (358.047 us; speedup 1.0000x reference)
//
#include <hip/hip_runtime.h>
#include <hip/hip_bf16.h>

typedef __attribute__((ext_vector_type(4))) float  f32x4;
typedef __attribute__((ext_vector_type(8))) _Float16 h16x8;

#define EMB 128
#define NSEQ 4096
#define NB 8
#define SCALE 0.08838834764831845f   // 1/sqrt(128)

// ---------------- prep: hi/lo split transposed weights ----------------
__global__ void prep_w(const float* __restrict__ wq, const float* __restrict__ wk,
                       const float* __restrict__ wv, _Float16* __restrict__ whiT,
                       _Float16* __restrict__ wloT) {
    int idx = blockIdx.x * 256 + threadIdx.x;          // 3*128*128 = 49152
    if (idx >= 3 * EMB * EMB) return;
    int widx = idx >> 14;
    int rem  = idx & 16383;
    int d = rem >> 7;
    int e = rem & 127;
    const float* w = (widx == 0) ? wq : (widx == 1) ? wk : wv;
    float v = w[d * 128 + e];
    _Float16 hi = (_Float16)v;
    _Float16 lo = (_Float16)(v - (float)hi);
    whiT[(size_t)widx * 16384 + (size_t)e * 128 + d] = hi;
    wloT[(size_t)widx * 16384 + (size_t)e * 128 + d] = lo;
}

// ---------------- QKV projection (hi/lo accurate) + mean-centering ----------------
// q: [tok][128] f16 = (Q - c_q)*SCALE ; k: [tok][128] f16 = K - c_k ;
// aq[tok] = c_q*128*SCALE ; ck[tok] = c_k ; vT: [b][e][n] f16.
__global__ __launch_bounds__(256) void qkv_proj(const float* __restrict__ x,
                                                const _Float16* __restrict__ whiT,
                                                const _Float16* __restrict__ wloT,
                                                _Float16* __restrict__ q,
                                                _Float16* __restrict__ k,
                                                _Float16* __restrict__ vT,
                                                float* __restrict__ aq,
                                                float* __restrict__ ck) {
    const int lane = threadIdx.x & 63;
    const int wave = threadIdx.x >> 6;
    const int g    = lane >> 4;
    const int lr   = lane & 15;
    const int rb   = blockIdx.x * 64 + wave * 16;

    h16x8 xhi[4], xlo[4];
    {
        const float* xrow = x + (size_t)(rb + lr) * EMB;
        #pragma unroll
        for (int kc = 0; kc < 4; ++kc) {
            const float* p = xrow + kc * 32 + g * 8;
            h16x8 ah, al;
            #pragma unroll
            for (int j = 0; j < 8; ++j) {
                float v = p[j];
                _Float16 h = (_Float16)v;
                ah[j] = h;
                al[j] = (_Float16)(v - (float)h);
            }
            xhi[kc] = ah; xlo[kc] = al;
        }
    }

    const int b  = rb >> 12;
    const int n0 = rb & 4095;

    for (int widx = 0; widx < 3; ++widx) {
        f32x4 acc[8];
        #pragma unroll
        for (int ct = 0; ct < 8; ++ct) acc[ct] = (f32x4){0.f, 0.f, 0.f, 0.f};

        const _Float16* wh = whiT + (size_t)widx * 16384;
        const _Float16* wl = wloT + (size_t)widx * 16384;
        #pragma unroll
        for (int kc = 0; kc < 4; ++kc) {
            #pragma unroll
            for (int ct = 0; ct < 8; ++ct) {
                size_t off = (size_t)(ct * 16 + lr) * 128 + kc * 32 + g * 8;
                h16x8 bh = *(const h16x8*)(wh + off);
                h16x8 bl = *(const h16x8*)(wl + off);
                acc[ct] = __builtin_amdgcn_mfma_f32_16x16x32_f16(xhi[kc], bh, acc[ct], 0, 0, 0);
                acc[ct] = __builtin_amdgcn_mfma_f32_16x16x32_f16(xlo[kc], bh, acc[ct], 0, 0, 0);
                acc[ct] = __builtin_amdgcn_mfma_f32_16x16x32_f16(xhi[kc], bl, acc[ct], 0, 0, 0);
            }
        }

        if (widx < 2) {
            // per-row mean over the 128 outputs (exact fp32)
            float c[4];
            #pragma unroll
            for (int r = 0; r < 4; ++r) {
                float rs = 0.f;
                #pragma unroll
                for (int ct = 0; ct < 8; ++ct) rs += acc[ct][r];
                #pragma unroll
                for (int off = 8; off; off >>= 1) rs += __shfl_xor(rs, off);
                c[r] = rs * (1.0f / 128.0f);
            }
            if (widx == 0) {
                #pragma unroll
                for (int ct = 0; ct < 8; ++ct)
                    #pragma unroll
                    for (int r = 0; r < 4; ++r) {
                        size_t row = rb + g * 4 + r;
                        q[row * 128 + ct * 16 + lr] = (_Float16)((acc[ct][r] - c[r]) * SCALE);
                    }
                if (lr == 0) {
                    #pragma unroll
                    for (int r = 0; r < 4; ++r) aq[rb + g * 4 + r] = c[r] * 128.0f * SCALE;
                }
            } else {
                #pragma unroll
                for (int ct = 0; ct < 8; ++ct)
                    #pragma unroll
                    for (int r = 0; r < 4; ++r) {
                        size_t row = rb + g * 4 + r;
                        k[row * 128 + ct * 16 + lr] = (_Float16)(acc[ct][r] - c[r]);
                    }
                if (lr == 0) {
                    #pragma unroll
                    for (int r = 0; r < 4; ++r) ck[rb + g * 4 + r] = c[r];
                }
            }
        } else {
            #pragma unroll
            for (int ct = 0; ct < 8; ++ct)
                #pragma unroll
                for (int r = 0; r < 4; ++r) {
                    int e  = ct * 16 + lr;
                    int nn = n0 + g * 4 + r;
                    vT[((size_t)b * EMB + e) * NSEQ + nn] = (_Float16)acc[ct][r];
                }
        }
    }
}

// ---------------- flash attention ----------------
// K tile: linear [64][256B] with XOR swizzle (off ^= (row&15)<<4) -> conflict-free.
__device__ __forceinline__ int kswz(int r, int cb) { return r * 256 + (cb ^ ((r & 15) << 4)); }

#define SPS 72    // P tile row stride (f16)

__global__ __launch_bounds__(256) void flash(const _Float16* __restrict__ q,
                                             const _Float16* __restrict__ k,
                                             const _Float16* __restrict__ vT,
                                             const float* __restrict__ aq,
                                             const float* __restrict__ ck,
                                             float* __restrict__ out) {
    __shared__ __align__(16) char KsB[64 * 256];
    __shared__ _Float16 Ps[4][16 * SPS];

    // bijective XCD swizzle: 512 blocks, 8 XCDs -> each XCD owns one batch
    const int bp  = blockIdx.x;
    const int bid = (bp & 7) * 64 + (bp >> 3);

    const int lane = threadIdx.x & 63;
    const int wave = threadIdx.x >> 6;
    const int g    = lane >> 4;
    const int lr   = lane & 15;
    const int b    = bid >> 6;
    const int qt   = bid & 63;
    const size_t qtok = (size_t)b * NSEQ + qt * 64 + wave * 16;

    // Q fragments (scale folded in) + rank-1 row coefficients
    h16x8 qf[4];
    #pragma unroll
    for (int kc = 0; kc < 4; ++kc)
        qf[kc] = *(const h16x8*)(q + (qtok + lr) * 128 + kc * 32 + g * 8);
    float aqr[4];
    #pragma unroll
    for (int r = 0; r < 4; ++r) aqr[r] = aq[qtok + g * 4 + r];

    f32x4 o[8];
    #pragma unroll
    for (int ct = 0; ct < 8; ++ct) o[ct] = (f32x4){0.f, 0.f, 0.f, 0.f};
    float m[4] = {-1e30f, -1e30f, -1e30f, -1e30f};
    float l[4] = {0.f, 0.f, 0.f, 0.f};

    const _Float16* kbat = k  + (size_t)b * NSEQ * EMB;
    const _Float16* vbat = vT + (size_t)b * EMB * NSEQ;
    const float*    ckb  = ck + (size_t)b * NSEQ;

    for (int t = 0; t < NSEQ / 64; ++t) {
        const int kvbase = t * 64;

        // per-lane rank-1 column coefficients (L1/L2-hot, 64B coalesced)
        float ckt[4];
        #pragma unroll
        for (int ct = 0; ct < 4; ++ct) ckt[ct] = ckb[kvbase + ct * 16 + lr];

        __syncthreads();   // protect previous tile's LDS reads
        {
            int r  = threadIdx.x >> 2;
            int c0 = (threadIdx.x & 3) * 64;    // byte col
            const char* src = (const char*)(kbat + (size_t)(kvbase + r) * EMB) + c0;
            #pragma unroll
            for (int i = 0; i < 4; ++i)
                *(h16x8*)(KsB + kswz(r, c0 + i * 16)) = *(const h16x8*)(src + i * 16);
        }
        __syncthreads();

        // S = (q~*scale) . k~  + aq*ck   (single f16 MFMA + exact fp32 rank-1)
        f32x4 s[4];
        #pragma unroll
        for (int ct = 0; ct < 4; ++ct) {
            f32x4 acc = (f32x4){0.f, 0.f, 0.f, 0.f};
            #pragma unroll
            for (int kc = 0; kc < 4; ++kc) {
                h16x8 kb = *(const h16x8*)(KsB + kswz(ct * 16 + lr, kc * 64 + g * 16));
                acc = __builtin_amdgcn_mfma_f32_16x16x32_f16(qf[kc], kb, acc, 0, 0, 0);
            }
            #pragma unroll
            for (int r = 0; r < 4; ++r) acc[r] += aqr[r] * ckt[ct];
            s[ct] = acc;
        }

        // issue V loads early (global, L2-resident) — latency hides under softmax
        h16x8 vreg[16];
        #pragma unroll
        for (int ct = 0; ct < 8; ++ct)
            #pragma unroll
            for (int kc = 0; kc < 2; ++kc)
                vreg[ct * 2 + kc] = *(const h16x8*)(vbat + (size_t)(ct * 16 + lr) * NSEQ
                                                    + kvbase + kc * 32 + g * 8);

        // online softmax
        float osc[4];
        #pragma unroll
        for (int r = 0; r < 4; ++r) {
            float tm = fmaxf(fmaxf(s[0][r], s[1][r]), fmaxf(s[2][r], s[3][r]));
            #pragma unroll
            for (int off = 8; off; off >>= 1) tm = fmaxf(tm, __shfl_xor(tm, off));
            float mn = fmaxf(m[r], tm);
            float sc = __expf(m[r] - mn);
            float rs = 0.f;
            #pragma unroll
            for (int ct = 0; ct < 4; ++ct) {
                float pv = __expf(s[ct][r] - mn);
                s[ct][r] = pv;
                rs += pv;
            }
            #pragma unroll
            for (int off = 8; off; off >>= 1) rs += __shfl_xor(rs, off);
            l[r] = l[r] * sc + rs;
            m[r] = mn;
            osc[r] = sc;
        }
        #pragma unroll
        for (int ct = 0; ct < 8; ++ct)
            #pragma unroll
            for (int r = 0; r < 4; ++r) o[ct][r] *= osc[r];

        // P -> LDS (C-layout -> A-layout), per-wave buffer
        _Float16* ps = &Ps[wave][0];
        #pragma unroll
        for (int ct = 0; ct < 4; ++ct)
            #pragma unroll
            for (int r = 0; r < 4; ++r)
                ps[(g * 4 + r) * SPS + ct * 16 + lr] = (_Float16)s[ct][r];

        h16x8 pa[2];
        #pragma unroll
        for (int kc = 0; kc < 2; ++kc)
            pa[kc] = *(const h16x8*)(ps + lr * SPS + kc * 32 + g * 8);

        // O += P V (V-frags already in registers)
        #pragma unroll
        for (int ct = 0; ct < 8; ++ct) {
            #pragma unroll
            for (int kc = 0; kc < 2; ++kc)
                o[ct] = __builtin_amdgcn_mfma_f32_16x16x32_f16(pa[kc], vreg[ct * 2 + kc], o[ct], 0, 0, 0);
        }
    }

    // epilogue
    #pragma unroll
    for (int ct = 0; ct < 8; ++ct)
        #pragma unroll
        for (int r = 0; r < 4; ++r) {
            size_t row = qtok + g * 4 + r;
            out[row * EMB + ct * 16 + lr] = o[ct][r] / l[r];
        }
}

extern "C" void kernel_launch(void* const* d_in, const int* in_sizes, int n_in,
                              void* d_out, int out_size, void* d_ws, size_t ws_size,
                              hipStream_t stream) {
    const float* x  = (const float*)d_in[0];
    const float* wq = (const float*)d_in[1];
    const float* wk = (const float*)d_in[2];
    const float* wv = (const float*)d_in[3];

    char* ws = (char*)d_ws;
    _Float16* q    = (_Float16*)(ws);                          // 8 MB
    _Float16* kk   = (_Float16*)(ws + 8388608);                // 8 MB
    _Float16* vT   = (_Float16*)(ws + 16777216);               // 8 MB
    float*    aq   = (float*)   (ws + 25165824);               // 128 KB
    float*    ck   = (float*)   (ws + 25296896);               // 128 KB
    _Float16* whiT = (_Float16*)(ws + 25427968);               // 96 KB
    _Float16* wloT = (_Float16*)(ws + 25526272);               // 96 KB

    prep_w<<<192, 256, 0, stream>>>(wq, wk, wv, whiT, wloT);
    qkv_proj<<<512, 256, 0, stream>>>(x, whiT, wloT, q, kk, vT, aq, ck);
    flash<<<512, 256, 0, stream>>>(q, kk, vT, aq, ck, (float*)d_out);
}

// Round 4
// 215.357 us; speedup vs baseline: 1.6626x; 1.6626x over previous
//
#include <hip/hip_runtime.h>
#include <hip/hip_bf16.h>

typedef __attribute__((ext_vector_type(4))) float  f32x4;
typedef __attribute__((ext_vector_type(8))) _Float16 h16x8;

#define EMB 128
#define NSEQ 4096
#define NB 8
#define SCALE 0.08838834764831845f   // 1/sqrt(128)

// ---------------- prep: hi/lo split transposed weights ----------------
__global__ void prep_w(const float* __restrict__ wq, const float* __restrict__ wk,
                       const float* __restrict__ wv, _Float16* __restrict__ whiT,
                       _Float16* __restrict__ wloT) {
    int idx = blockIdx.x * 256 + threadIdx.x;          // 3*128*128 = 49152
    if (idx >= 3 * EMB * EMB) return;
    int widx = idx >> 14;
    int rem  = idx & 16383;
    int d = rem >> 7;
    int e = rem & 127;
    const float* w = (widx == 0) ? wq : (widx == 1) ? wk : wv;
    float v = w[d * 128 + e];
    _Float16 hi = (_Float16)v;
    _Float16 lo = (_Float16)(v - (float)hi);
    whiT[(size_t)widx * 16384 + (size_t)e * 128 + d] = hi;
    wloT[(size_t)widx * 16384 + (size_t)e * 128 + d] = lo;
}

// ---------------- QKV projection, grid split over widx for occupancy ----------------
// q: [tok][128] f16 = (Q - c_q)*SCALE ; k: [tok][128] f16 = K - c_k ;
// aq[tok] = c_q*128*SCALE ; ck[tok] = c_k ; vT: [b][e][n] f16.
__global__ __launch_bounds__(256) void qkv_proj(const float* __restrict__ x,
                                                const _Float16* __restrict__ whiT,
                                                const _Float16* __restrict__ wloT,
                                                _Float16* __restrict__ q,
                                                _Float16* __restrict__ k,
                                                _Float16* __restrict__ vT,
                                                float* __restrict__ aq,
                                                float* __restrict__ ck) {
    const int widx = blockIdx.x >> 9;          // 0,1,2
    const int blk  = blockIdx.x & 511;
    const int lane = threadIdx.x & 63;
    const int wave = threadIdx.x >> 6;
    const int g    = lane >> 4;
    const int lr   = lane & 15;
    const int rb   = blk * 64 + wave * 16;

    h16x8 xhi[4], xlo[4];
    {
        const float* xrow = x + (size_t)(rb + lr) * EMB;
        #pragma unroll
        for (int kc = 0; kc < 4; ++kc) {
            const float* p = xrow + kc * 32 + g * 8;
            h16x8 ah, al;
            #pragma unroll
            for (int j = 0; j < 8; ++j) {
                float v = p[j];
                _Float16 h = (_Float16)v;
                ah[j] = h;
                al[j] = (_Float16)(v - (float)h);
            }
            xhi[kc] = ah;
            if (widx < 2) xlo[kc] = al;
        }
    }

    const int b  = rb >> 12;
    const int n0 = rb & 4095;

    f32x4 acc[8];
    #pragma unroll
    for (int ct = 0; ct < 8; ++ct) acc[ct] = (f32x4){0.f, 0.f, 0.f, 0.f};

    const _Float16* wh = whiT + (size_t)widx * 16384;
    const _Float16* wl = wloT + (size_t)widx * 16384;
    #pragma unroll
    for (int kc = 0; kc < 4; ++kc) {
        #pragma unroll
        for (int ct = 0; ct < 8; ++ct) {
            size_t off = (size_t)(ct * 16 + lr) * 128 + kc * 32 + g * 8;
            h16x8 bh = *(const h16x8*)(wh + off);
            acc[ct] = __builtin_amdgcn_mfma_f32_16x16x32_f16(xhi[kc], bh, acc[ct], 0, 0, 0);
            if (widx < 2) {
                h16x8 bl = *(const h16x8*)(wl + off);
                acc[ct] = __builtin_amdgcn_mfma_f32_16x16x32_f16(xlo[kc], bh, acc[ct], 0, 0, 0);
                acc[ct] = __builtin_amdgcn_mfma_f32_16x16x32_f16(xhi[kc], bl, acc[ct], 0, 0, 0);
            }
        }
    }

    if (widx < 2) {
        float c[4];
        #pragma unroll
        for (int r = 0; r < 4; ++r) {
            float rs = 0.f;
            #pragma unroll
            for (int ct = 0; ct < 8; ++ct) rs += acc[ct][r];
            #pragma unroll
            for (int off = 8; off; off >>= 1) rs += __shfl_xor(rs, off);
            c[r] = rs * (1.0f / 128.0f);
        }
        if (widx == 0) {
            #pragma unroll
            for (int ct = 0; ct < 8; ++ct)
                #pragma unroll
                for (int r = 0; r < 4; ++r) {
                    size_t row = rb + g * 4 + r;
                    q[row * 128 + ct * 16 + lr] = (_Float16)((acc[ct][r] - c[r]) * SCALE);
                }
            if (lr == 0) {
                #pragma unroll
                for (int r = 0; r < 4; ++r) aq[rb + g * 4 + r] = c[r] * 128.0f * SCALE;
            }
        } else {
            #pragma unroll
            for (int ct = 0; ct < 8; ++ct)
                #pragma unroll
                for (int r = 0; r < 4; ++r) {
                    size_t row = rb + g * 4 + r;
                    k[row * 128 + ct * 16 + lr] = (_Float16)(acc[ct][r] - c[r]);
                }
            if (lr == 0) {
                #pragma unroll
                for (int r = 0; r < 4; ++r) ck[rb + g * 4 + r] = c[r];
            }
        }
    } else {
        #pragma unroll
        for (int ct = 0; ct < 8; ++ct)
            #pragma unroll
            for (int r = 0; r < 4; ++r) {
                int e  = ct * 16 + lr;
                int nn = n0 + g * 4 + r;
                vT[((size_t)b * EMB + e) * NSEQ + nn] = (_Float16)acc[ct][r];
            }
    }
}

// ---------------- flash attention (software-pipelined staging) ----------------
#define SPS 72    // P tile row stride (f16)

__global__ __launch_bounds__(256) void flash(const _Float16* __restrict__ q,
                                             const _Float16* __restrict__ k,
                                             const _Float16* __restrict__ vT,
                                             const float* __restrict__ aq,
                                             const float* __restrict__ ck,
                                             float* __restrict__ out) {
    __shared__ __align__(16) char KsB[2][16384];   // 64 rows x 256 B, XOR-swizzled
    __shared__ __align__(16) char VsB[2][16384];   // 128 rows x 128 B, XOR-swizzled
    __shared__ _Float16 Ps[4][16 * SPS];

    // bijective XCD swizzle: each XCD owns one batch
    const int bp  = blockIdx.x;
    const int bid = (bp & 7) * 64 + (bp >> 3);

    const int lane = threadIdx.x & 63;
    const int wave = threadIdx.x >> 6;
    const int g    = lane >> 4;
    const int lr   = lane & 15;
    const int b    = bid >> 6;
    const int qt   = bid & 63;
    const size_t qtok = (size_t)b * NSEQ + qt * 64 + wave * 16;

    const _Float16* kbat = k  + (size_t)b * NSEQ * EMB;
    const _Float16* vbat = vT + (size_t)b * EMB * NSEQ;
    const float*    ckb  = ck + (size_t)b * NSEQ;

    // Q fragments (scale folded) + rank-1 row coefficients
    h16x8 qf[4];
    #pragma unroll
    for (int kc = 0; kc < 4; ++kc)
        qf[kc] = *(const h16x8*)(q + (qtok + lr) * 128 + kc * 32 + g * 8);
    float aqr[4];
    #pragma unroll
    for (int r = 0; r < 4; ++r) aqr[r] = aq[qtok + g * 4 + r];

    // staging geometry (per-lane, fixed for the whole kernel)
    const int krow  = wave * 16 + (lane >> 2);        // K: 16 rows/wave x 256 B
    const int kcolB = (lane & 3) * 64;
    const int vrow  = wave * 32 + (lane >> 1);        // V: 32 rows/wave x 128 B
    const int vcolB = (lane & 1) * 64;
    const char* kp = (const char*)(kbat + (size_t)krow * EMB) + kcolB;   // +16384 B/tile
    const char* vp = (const char*)(vbat + (size_t)vrow * NSEQ) + vcolB;  // +128 B/tile
    const int kdst = krow * 256;
    const int vdst = vrow * 128;

    h16x8 stK[4], stV[4];

    // prologue: stage tile 0
    #pragma unroll
    for (int i = 0; i < 4; ++i) stK[i] = *(const h16x8*)(kp + i * 16);
    #pragma unroll
    for (int i = 0; i < 4; ++i) stV[i] = *(const h16x8*)(vp + i * 16);
    #pragma unroll
    for (int i = 0; i < 4; ++i)
        *(h16x8*)(KsB[0] + kdst + ((kcolB + i * 16) ^ ((krow & 15) << 4))) = stK[i];
    #pragma unroll
    for (int i = 0; i < 4; ++i)
        *(h16x8*)(VsB[0] + vdst + ((vcolB + i * 16) ^ ((vrow & 7) << 4))) = stV[i];
    __syncthreads();

    f32x4 o[8];
    #pragma unroll
    for (int ct = 0; ct < 8; ++ct) o[ct] = (f32x4){0.f, 0.f, 0.f, 0.f};
    float m[4] = {-1e30f, -1e30f, -1e30f, -1e30f};
    float l[4] = {0.f, 0.f, 0.f, 0.f};

    int cur = 0;
    for (int t = 0; t < NSEQ / 64; ++t) {
        // issue next tile's staging loads (latency hides under compute)
        kp += 16384; vp += 128;
        if (t + 1 < NSEQ / 64) {
            #pragma unroll
            for (int i = 0; i < 4; ++i) stK[i] = *(const h16x8*)(kp + i * 16);
            #pragma unroll
            for (int i = 0; i < 4; ++i) stV[i] = *(const h16x8*)(vp + i * 16);
        }

        // per-lane rank-1 column coefficients
        float ckt[4];
        #pragma unroll
        for (int ct = 0; ct < 4; ++ct) ckt[ct] = ckb[t * 64 + ct * 16 + lr];

        // S = q~.k~ + aq*ck
        const char* Kb = KsB[cur];
        f32x4 s[4];
        #pragma unroll
        for (int ct = 0; ct < 4; ++ct) {
            f32x4 acc = (f32x4){0.f, 0.f, 0.f, 0.f};
            #pragma unroll
            for (int kc = 0; kc < 4; ++kc) {
                h16x8 kb = *(const h16x8*)(Kb + (ct * 16 + lr) * 256 + ((kc * 64 + g * 16) ^ (lr << 4)));
                acc = __builtin_amdgcn_mfma_f32_16x16x32_f16(qf[kc], kb, acc, 0, 0, 0);
            }
            #pragma unroll
            for (int r = 0; r < 4; ++r) acc[r] += aqr[r] * ckt[ct];
            s[ct] = acc;
        }

        // online softmax
        float osc[4];
        #pragma unroll
        for (int r = 0; r < 4; ++r) {
            float tm = fmaxf(fmaxf(s[0][r], s[1][r]), fmaxf(s[2][r], s[3][r]));
            #pragma unroll
            for (int off = 8; off; off >>= 1) tm = fmaxf(tm, __shfl_xor(tm, off));
            float mn = fmaxf(m[r], tm);
            float sc = __expf(m[r] - mn);
            float rs = 0.f;
            #pragma unroll
            for (int ct = 0; ct < 4; ++ct) {
                float pv = __expf(s[ct][r] - mn);
                s[ct][r] = pv;
                rs += pv;
            }
            #pragma unroll
            for (int off = 8; off; off >>= 1) rs += __shfl_xor(rs, off);
            l[r] = l[r] * sc + rs;
            m[r] = mn;
            osc[r] = sc;
        }
        #pragma unroll
        for (int ct = 0; ct < 8; ++ct)
            #pragma unroll
            for (int r = 0; r < 4; ++r) o[ct][r] *= osc[r];

        // P -> LDS (C-layout -> A-layout), per-wave buffer
        _Float16* ps = &Ps[wave][0];
        #pragma unroll
        for (int ct = 0; ct < 4; ++ct)
            #pragma unroll
            for (int r = 0; r < 4; ++r)
                ps[(g * 4 + r) * SPS + ct * 16 + lr] = (_Float16)s[ct][r];

        h16x8 pa[2];
        #pragma unroll
        for (int kc = 0; kc < 2; ++kc)
            pa[kc] = *(const h16x8*)(ps + lr * SPS + kc * 32 + g * 8);

        // O += P V (V frags from swizzled LDS)
        const char* Vb = VsB[cur];
        #pragma unroll
        for (int ct = 0; ct < 8; ++ct) {
            #pragma unroll
            for (int kc = 0; kc < 2; ++kc) {
                h16x8 vb = *(const h16x8*)(Vb + (ct * 16 + lr) * 128 + ((kc * 64 + g * 16) ^ ((lr & 7) << 4)));
                o[ct] = __builtin_amdgcn_mfma_f32_16x16x32_f16(pa[kc], vb, o[ct], 0, 0, 0);
            }
        }

        // write next tile into the other buffer, one barrier per tile
        if (t + 1 < NSEQ / 64) {
            char* kb = (char*)KsB[cur ^ 1];
            char* vb = (char*)VsB[cur ^ 1];
            #pragma unroll
            for (int i = 0; i < 4; ++i)
                *(h16x8*)(kb + kdst + ((kcolB + i * 16) ^ ((krow & 15) << 4))) = stK[i];
            #pragma unroll
            for (int i = 0; i < 4; ++i)
                *(h16x8*)(vb + vdst + ((vcolB + i * 16) ^ ((vrow & 7) << 4))) = stV[i];
        }
        __syncthreads();
        cur ^= 1;
    }

    // epilogue
    #pragma unroll
    for (int ct = 0; ct < 8; ++ct)
        #pragma unroll
        for (int r = 0; r < 4; ++r) {
            size_t row = qtok + g * 4 + r;
            out[row * EMB + ct * 16 + lr] = o[ct][r] / l[r];
        }
}

extern "C" void kernel_launch(void* const* d_in, const int* in_sizes, int n_in,
                              void* d_out, int out_size, void* d_ws, size_t ws_size,
                              hipStream_t stream) {
    const float* x  = (const float*)d_in[0];
    const float* wq = (const float*)d_in[1];
    const float* wk = (const float*)d_in[2];
    const float* wv = (const float*)d_in[3];

    char* ws = (char*)d_ws;
    _Float16* q    = (_Float16*)(ws);                          // 8 MB
    _Float16* kk   = (_Float16*)(ws + 8388608);                // 8 MB
    _Float16* vT   = (_Float16*)(ws + 16777216);               // 8 MB
    float*    aq   = (float*)   (ws + 25165824);               // 128 KB
    float*    ck   = (float*)   (ws + 25296896);               // 128 KB
    _Float16* whiT = (_Float16*)(ws + 25427968);               // 96 KB
    _Float16* wloT = (_Float16*)(ws + 25526272);               // 96 KB

    prep_w<<<192, 256, 0, stream>>>(wq, wk, wv, whiT, wloT);
    qkv_proj<<<1536, 256, 0, stream>>>(x, whiT, wloT, q, kk, vT, aq, ck);
    flash<<<512, 256, 0, stream>>>(q, kk, vT, aq, ck, (float*)d_out);
}